// Round 2
// baseline (630.104 us; speedup 1.0000x reference)
//
#include <hip/hip_runtime.h>
#include <math.h>

#define NUM_HOP 3
#define VOCAB   32000
#define DIM     512
#define MEM     60
#define BS      64
#define STORY   50
#define SENT    32
#define QLEN    16

#define TBL     ((size_t)VOCAB * DIM)

typedef _Float16 v8h __attribute__((ext_vector_type(8)));   // 8 fp16
typedef float    v4f __attribute__((ext_vector_type(4)));

static __device__ __forceinline__ ushort f2h(float x) {
    union { _Float16 h; ushort u; } v;
    v.h = (_Float16)x;           // RNE f32->f16
    return v.u;
}

// ---------------------------------------------------------------------------
// u0[b,:] = sum_t A0[query[b,t]] (skip idx 0); also emit U2h = fp16([u; u*ds])
// grid: BS x 512
__global__ __launch_bounds__(512) void k_prep(const float* __restrict__ A0,
                                              const int*   __restrict__ query,
                                              float*       __restrict__ u,
                                              ushort*      __restrict__ U2h) {
    const int b = blockIdx.x, tid = threadIdx.x;
    const int* q = query + b * QLEN;
    int idx[QLEN];
    #pragma unroll
    for (int t = 0; t < QLEN; ++t) idx[t] = q[t];
    float acc = 0.f;
    #pragma unroll
    for (int t = 0; t < QLEN; ++t)
        if (idx[t] != 0) acc += A0[(size_t)idx[t] * DIM + tid];
    u[(size_t)b * DIM + tid] = acc;
    U2h[(size_t)b * DIM + tid] = f2h(acc);
    U2h[(size_t)(BS + b) * DIM + tid] = f2h(acc * (float)(tid + 1) * (1.0f / (float)DIM));
}

// ---------------------------------------------------------------------------
// Z2[v][b] = { A_h[v].u_b , A_h[v].(u_b*ds) }  via fp16 MFMA, N=128.
// blocks 0..499: 64 vocab rows each. block 500: T_A rows (-> Z2 rows 32000+s).
__global__ __launch_bounds__(256) void k_z(const float*  __restrict__ Ah,
                                           const float*  __restrict__ T_A,
                                           const ushort* __restrict__ U2h,
                                           float2*       __restrict__ Z2) {
    __shared__ ushort Ah16[64 * 128];   // 16 KB
    __shared__ ushort Uh16[128 * 128];  // 32 KB
    const int tid  = threadIdx.x;
    const int lane = tid & 63;
    const int wave = tid >> 6;
    const int i16  = lane & 15;
    const int quad = lane >> 4;
    const bool ist = (blockIdx.x == 500);
    const int row0 = blockIdx.x * 64;

    v4f acc[8];
    #pragma unroll
    for (int nt = 0; nt < 8; ++nt) acc[nt] = (v4f){0.f, 0.f, 0.f, 0.f};

    for (int ko = 0; ko < 4; ++ko) {
        __syncthreads();
        // stage A-tile (64 rows x 128 k), f32 -> fp16, XOR-swizzled
        #pragma unroll
        for (int it = 0; it < 4; ++it) {
            const int i = it * 256 + tid;
            const int r = i >> 4, g = i & 15;
            const int rsrc = ist ? (r < MEM ? r : MEM - 1) : (row0 + r);
            const float* src = (ist ? T_A : Ah) + (size_t)rsrc * DIM + ko * 128 + g * 8;
            const float4 f0 = *(const float4*)(src);
            const float4 f1 = *(const float4*)(src + 4);
            union { ushort h[8]; uint4 q; } pk;
            pk.h[0] = f2h(f0.x); pk.h[1] = f2h(f0.y);
            pk.h[2] = f2h(f0.z); pk.h[3] = f2h(f0.w);
            pk.h[4] = f2h(f1.x); pk.h[5] = f2h(f1.y);
            pk.h[6] = f2h(f1.z); pk.h[7] = f2h(f1.w);
            *(uint4*)(&Ah16[r * 128 + ((g ^ (r & 7)) * 8)]) = pk.q;
        }
        // stage U-tile (128 rows x 128 k), already fp16
        #pragma unroll
        for (int it = 0; it < 8; ++it) {
            const int i = it * 256 + tid;
            const int n = i >> 4, g = i & 15;
            const uint4 v = *(const uint4*)(U2h + (size_t)n * DIM + ko * 128 + g * 8);
            *(uint4*)(&Uh16[n * 128 + ((g ^ (n & 7)) * 8)]) = v;
        }
        __syncthreads();

        const int arow = wave * 16 + i16;
        #pragma unroll
        for (int ki = 0; ki < 4; ++ki) {
            const int ga = ki * 4 + quad;
            const v8h a = *(const v8h*)(&Ah16[arow * 128 + ((ga ^ (arow & 7)) * 8)]);
            #pragma unroll
            for (int nt = 0; nt < 8; ++nt) {
                const int n = nt * 16 + i16;
                const v8h bb = *(const v8h*)(&Uh16[n * 128 + ((ga ^ (n & 7)) * 8)]);
                acc[nt] = __builtin_amdgcn_mfma_f32_16x16x32_f16(a, bb, acc[nt], 0, 0, 0);
            }
        }
    }

    const int vbase = row0 + wave * 16 + quad * 4;
    #pragma unroll
    for (int nt = 0; nt < 4; ++nt) {
        const int b = nt * 16 + i16;
        #pragma unroll
        for (int r = 0; r < 4; ++r)
            Z2[(size_t)(vbase + r) * BS + b] = make_float2(acc[nt][r], acc[nt + 4][r]);
    }
}

// ---------------------------------------------------------------------------
// score[b,s] = sum_w (aw*zu - bw*zd) + TZ[s][b]; softmax over s -> p[b][s].
// grid: BS x 256 (4 waves, 2 sentences per wave-iter).
__global__ __launch_bounds__(256) void k_score(const int*    __restrict__ ctx,
                                               const float2* __restrict__ Z2,
                                               float*        __restrict__ p) {
    const int b    = blockIdx.x;
    const int tid  = threadIdx.x;
    const int wave = tid >> 6;
    const int lane = tid & 63;
    const int w    = lane & 31;
    const int half = lane >> 5;
    __shared__ float ss[64];

    const float aw = 1.0f - (float)(w + 1) * (1.0f / 32.0f);
    const float bw = 1.0f - (float)(w + 1) * (1.0f / 16.0f);

    #pragma unroll
    for (int i = 0; i < 7; ++i) {
        const int s = i * 8 + wave * 2 + half;
        float val = 0.f;
        if (s < STORY) {
            const int idx = ctx[b * (STORY * SENT) + s * SENT + w];
            if (idx != 0) {
                const float2 z = Z2[(size_t)idx * BS + b];
                val = aw * z.x - bw * z.y;
            }
        }
        val += __shfl_down(val, 16); val += __shfl_down(val, 8);
        val += __shfl_down(val, 4);  val += __shfl_down(val, 2);
        val += __shfl_down(val, 1);
        if (w == 0 && s < STORY)
            ss[s] = val + Z2[(size_t)(VOCAB + s) * BS + b].x;   // + T_A[s].u_b
    }
    __syncthreads();

    if (tid < 64) {
        const float v = (tid < STORY) ? ss[tid] : -1e30f;
        float mx = v;
        for (int off = 32; off; off >>= 1) mx = fmaxf(mx, __shfl_down(mx, off));
        mx = __shfl(mx, 0);
        const float e = (tid < STORY) ? __expf(v - mx) : 0.f;
        float sm = e;
        for (int off = 32; off; off >>= 1) sm += __shfl_down(sm, off);
        sm = __shfl(sm, 0);
        p[b * 64 + tid] = e / sm;   // tid >= STORY stores 0
    }
}

// ---------------------------------------------------------------------------
// u[b] += sum_{s,w} p[b,s] * A_{h+1}[ctx[b,s,w]]; also refresh U2h.
// grid: BS*8 blocks (b, d-chunk of 64) x 256 (4 waves x 400 words each).
__global__ __launch_bounds__(256) void k_cupd(const int*   __restrict__ ctx,
                                              const float* __restrict__ p,
                                              const float* __restrict__ An,
                                              float*       __restrict__ u,
                                              ushort*      __restrict__ U2h) {
    const int b    = blockIdx.x >> 3;
    const int dc   = blockIdx.x & 7;
    const int tid  = threadIdx.x;
    const int wave = tid >> 6;
    const int lane = tid & 63;
    const int d    = dc * 64 + lane;
    __shared__ float part[4][64];

    const int*   cb = ctx + b * (STORY * SENT);
    const float* pb = p + b * 64;

    float acc = 0.f;
    for (int t0 = wave * 400; t0 < wave * 400 + 400; t0 += 8) {
        int idx[8]; float ps[8], av[8];
        #pragma unroll
        for (int j = 0; j < 8; ++j) idx[j] = cb[t0 + j];
        #pragma unroll
        for (int j = 0; j < 8; ++j) av[j] = An[(size_t)idx[j] * DIM + d];
        #pragma unroll
        for (int j = 0; j < 8; ++j) ps[j] = (idx[j] != 0) ? pb[(t0 + j) >> 5] : 0.f;
        #pragma unroll
        for (int j = 0; j < 8; ++j) acc = fmaf(av[j], ps[j], acc);
    }
    part[wave][lane] = acc;
    __syncthreads();

    if (tid < 64) {
        const int dd = dc * 64 + tid;
        const float un = u[(size_t)b * DIM + dd]
                       + part[0][tid] + part[1][tid] + part[2][tid] + part[3][tid];
        u[(size_t)b * DIM + dd] = un;
        U2h[(size_t)b * DIM + dd] = f2h(un);
        U2h[(size_t)(BS + b) * DIM + dd] = f2h(un * (float)(dd + 1) * (1.0f / (float)DIM));
    }
}

// ---------------------------------------------------------------------------
// logits[b,v] = u_b . A3[v] in exact f32 (VALU). LDS-transposed tiles.
// grid: 500 x 256. Row v=0 forced to 0 (ref zeroes padding row).
#define DCH 64
__global__ __launch_bounds__(256) void k_logits(const float* __restrict__ A3,
                                                const float* __restrict__ u,
                                                float*       __restrict__ out) {
    __shared__ float AT[DCH][64];
    __shared__ float UT[DCH][64];
    const int tid = threadIdx.x;
    const int v0  = blockIdx.x * 64;
    const int vq  = (tid & 15) * 4;     // v offset in tile
    const int bq  = (tid >> 4) * 4;     // b offset
    const int lr  = tid & 63;           // staging row
    const int dg  = tid >> 6;           // staging d-group (0..3)

    float4 acc[4];                      // acc[j] = out[bq+j][v0+vq .. +3]
    #pragma unroll
    for (int j = 0; j < 4; ++j) acc[j] = make_float4(0.f, 0.f, 0.f, 0.f);

    for (int ko = 0; ko < 8; ++ko) {
        __syncthreads();
        #pragma unroll
        for (int k4 = 0; k4 < 4; ++k4) {
            const int dd = dg * 16 + k4 * 4;
            const float4 a = *(const float4*)(A3 + (size_t)(v0 + lr) * DIM + ko * DCH + dd);
            AT[dd + 0][lr] = a.x; AT[dd + 1][lr] = a.y;
            AT[dd + 2][lr] = a.z; AT[dd + 3][lr] = a.w;
            const float4 b = *(const float4*)(u + (size_t)lr * DIM + ko * DCH + dd);
            UT[dd + 0][lr] = b.x; UT[dd + 1][lr] = b.y;
            UT[dd + 2][lr] = b.z; UT[dd + 3][lr] = b.w;
        }
        __syncthreads();
        #pragma unroll 4
        for (int dd = 0; dd < DCH; ++dd) {
            const float4 a4 = *(const float4*)(&AT[dd][vq]);
            const float4 u4 = *(const float4*)(&UT[dd][bq]);
            acc[0].x = fmaf(a4.x, u4.x, acc[0].x); acc[0].y = fmaf(a4.y, u4.x, acc[0].y);
            acc[0].z = fmaf(a4.z, u4.x, acc[0].z); acc[0].w = fmaf(a4.w, u4.x, acc[0].w);
            acc[1].x = fmaf(a4.x, u4.y, acc[1].x); acc[1].y = fmaf(a4.y, u4.y, acc[1].y);
            acc[1].z = fmaf(a4.z, u4.y, acc[1].z); acc[1].w = fmaf(a4.w, u4.y, acc[1].w);
            acc[2].x = fmaf(a4.x, u4.z, acc[2].x); acc[2].y = fmaf(a4.y, u4.z, acc[2].y);
            acc[2].z = fmaf(a4.z, u4.z, acc[2].z); acc[2].w = fmaf(a4.w, u4.z, acc[2].w);
            acc[3].x = fmaf(a4.x, u4.w, acc[3].x); acc[3].y = fmaf(a4.y, u4.w, acc[3].y);
            acc[3].z = fmaf(a4.z, u4.w, acc[3].z); acc[3].w = fmaf(a4.w, u4.w, acc[3].w);
        }
    }

    if (v0 + vq == 0) {   // padding row: logits[:,0] = 0
        acc[0].x = 0.f; acc[1].x = 0.f; acc[2].x = 0.f; acc[3].x = 0.f;
    }
    #pragma unroll
    for (int j = 0; j < 4; ++j)
        *(float4*)(out + (size_t)(bq + j) * VOCAB + v0 + vq) = acc[j];
}

// ---------------------------------------------------------------------------
// in-place row softmax over VOCAB; row cached in registers, exp computed once.
__global__ __launch_bounds__(1024) void k_vsm(float* __restrict__ out) {
    const int b   = blockIdx.x;
    const int tid = threadIdx.x;
    float* row = out + (size_t)b * VOCAB;
    __shared__ float red[16];
    __shared__ float bc;

    float x[32];
    #pragma unroll
    for (int k = 0; k < 31; ++k) x[k] = row[tid + k * 1024];
    const bool extra = (tid < VOCAB - 31 * 1024);
    x[31] = extra ? row[tid + 31 * 1024] : -1e30f;

    float mx = -1e30f;
    #pragma unroll
    for (int k = 0; k < 32; ++k) mx = fmaxf(mx, x[k]);
    for (int off = 32; off; off >>= 1) mx = fmaxf(mx, __shfl_down(mx, off));
    if ((tid & 63) == 0) red[tid >> 6] = mx;
    __syncthreads();
    if (tid < 64) {
        float v = (tid < 16) ? red[tid] : -1e30f;
        for (int off = 8; off; off >>= 1) v = fmaxf(v, __shfl_down(v, off));
        if (tid == 0) bc = v;
    }
    __syncthreads();
    mx = bc;
    __syncthreads();

    float sum = 0.f;
    #pragma unroll
    for (int k = 0; k < 32; ++k) { x[k] = __expf(x[k] - mx); sum += x[k]; }
    if (!extra) sum -= x[31];
    for (int off = 32; off; off >>= 1) sum += __shfl_down(sum, off);
    if ((tid & 63) == 0) red[tid >> 6] = sum;
    __syncthreads();
    if (tid < 64) {
        float v = (tid < 16) ? red[tid] : 0.f;
        for (int off = 8; off; off >>= 1) v += __shfl_down(v, off);
        if (tid == 0) bc = v;
    }
    __syncthreads();
    const float inv = 1.0f / bc;

    #pragma unroll
    for (int k = 0; k < 31; ++k) row[tid + k * 1024] = x[k] * inv;
    if (extra) row[tid + 31 * 1024] = x[31] * inv;
}

// ---------------------------------------------------------------------------
extern "C" void kernel_launch(void* const* d_in, const int* in_sizes, int n_in,
                              void* d_out, int out_size, void* d_ws, size_t ws_size,
                              hipStream_t stream) {
    const int*   ctx   = (const int*)d_in[0];    // (BS, STORY, SENT)
    const int*   query = (const int*)d_in[1];    // (BS, QLEN)
    const float* A     = (const float*)d_in[2];  // (4, VOCAB, DIM)
    const float* T_A   = (const float*)d_in[3];  // (1, MEM, DIM)
    float* out = (float*)d_out;                  // (BS, VOCAB)

    float*  u   = (float*)d_ws;                      // 64*512 f32
    ushort* U2h = (ushort*)(u + BS * DIM);           // 128*512 fp16
    float*  p   = (float*)(U2h + 2 * BS * DIM);      // 64*64 f32
    float2* Z2  = (float2*)(p + BS * 64);            // 32064*64 float2 (~16.4 MB)

    k_prep<<<BS, DIM, 0, stream>>>(A, query, u, U2h);
    for (int h = 0; h < NUM_HOP; ++h) {
        k_z    <<<501, 256, 0, stream>>>(A + (size_t)h * TBL, T_A, U2h, Z2);
        k_score<<<BS, 256, 0, stream>>>(ctx, Z2, p);
        k_cupd <<<BS * 8, 256, 0, stream>>>(ctx, p, A + (size_t)(h + 1) * TBL, u, U2h);
    }
    k_logits<<<500, 256, 0, stream>>>(A + 3 * TBL, u, out);
    k_vsm  <<<BS, 1024, 0, stream>>>(out);
}

// Round 3
// 550.848 us; speedup vs baseline: 1.1439x; 1.1439x over previous
//
#include <hip/hip_runtime.h>
#include <math.h>

#define NUM_HOP 3
#define VOCAB   32000
#define DIM     512
#define MEM     60
#define BS      64
#define STORY   50
#define SENT    32
#define QLEN    16

#define TBL     ((size_t)VOCAB * DIM)

typedef _Float16 v8h __attribute__((ext_vector_type(8)));   // 8 fp16
typedef float    v4f __attribute__((ext_vector_type(4)));

static __device__ __forceinline__ ushort f2h(float x) {
    union { _Float16 h; ushort u; } v;
    v.h = (_Float16)x;           // RNE f32->f16
    return v.u;
}

// ---------------------------------------------------------------------------
// u0[b,:] = sum_t A0[query[b,t]] (skip idx 0). grid: BS x 512
__global__ __launch_bounds__(512) void k_prep(const float* __restrict__ A0,
                                              const int*   __restrict__ query,
                                              float*       __restrict__ u) {
    const int b = blockIdx.x, tid = threadIdx.x;
    const int* q = query + b * QLEN;
    int idx[QLEN];
    #pragma unroll
    for (int t = 0; t < QLEN; ++t) idx[t] = q[t];
    float acc = 0.f;
    #pragma unroll
    for (int t = 0; t < QLEN; ++t)
        if (idx[t] != 0) acc += A0[(size_t)idx[t] * DIM + tid];
    u[(size_t)b * DIM + tid] = acc;
}

// ---------------------------------------------------------------------------
// Z[v][0..63] = A_h[v].u_b ; Z[v][64..127] = A_h[v].(u_b*ds)  (fp16 MFMA)
// blocks 0..999: 32 vocab rows each. blocks 1000,1001: T_A rows -> Z rows 32000+.
// U operand staged on-the-fly from f32 u (ds-scale for plane 1).
__global__ __launch_bounds__(256) void k_z(const float* __restrict__ Ah,
                                           const float* __restrict__ T_A,
                                           const float* __restrict__ u,
                                           float*       __restrict__ Z) {
    __shared__ ushort Ahl[32 * 128];    //  8 KB
    __shared__ ushort Uhl[128 * 128];   // 32 KB
    const int tid  = threadIdx.x;
    const int lane = tid & 63;
    const int wave = tid >> 6;
    const int i16  = lane & 15;
    const int quad = lane >> 4;
    const int mt   = wave & 1;          // m-tile (16 rows)
    const int nh   = wave >> 1;         // 0: zu cols, 1: zd cols
    const bool ist = (blockIdx.x >= 1000);
    const int row0 = blockIdx.x * 32;

    v4f acc[4];
    #pragma unroll
    for (int nt = 0; nt < 4; ++nt) acc[nt] = (v4f){0.f, 0.f, 0.f, 0.f};

    for (int ko = 0; ko < 4; ++ko) {
        __syncthreads();
        // stage A-tile (32 rows x 128 k), f32 -> fp16, XOR-swizzled
        #pragma unroll
        for (int it = 0; it < 2; ++it) {
            const int i = it * 256 + tid;
            const int r = i >> 4, g = i & 15;
            const float* src;
            if (ist) {
                int t = row0 + r - VOCAB; if (t > MEM - 1) t = MEM - 1;
                src = T_A + (size_t)t * DIM + ko * 128 + g * 8;
            } else {
                src = Ah + (size_t)(row0 + r) * DIM + ko * 128 + g * 8;
            }
            const float4 f0 = *(const float4*)(src);
            const float4 f1 = *(const float4*)(src + 4);
            union { ushort h[8]; uint4 q; } pk;
            pk.h[0] = f2h(f0.x); pk.h[1] = f2h(f0.y);
            pk.h[2] = f2h(f0.z); pk.h[3] = f2h(f0.w);
            pk.h[4] = f2h(f1.x); pk.h[5] = f2h(f1.y);
            pk.h[6] = f2h(f1.z); pk.h[7] = f2h(f1.w);
            *(uint4*)(&Ahl[r * 128 + ((g ^ (r & 7)) * 8)]) = pk.q;
        }
        // stage U-tile (128 rows x 128 k) from f32 u; rows >=64 get ds scale
        #pragma unroll
        for (int it = 0; it < 8; ++it) {
            const int i = it * 256 + tid;
            const int n = i >> 4, g = i & 15;
            const int k = ko * 128 + g * 8;
            const float* su = u + (size_t)(n & 63) * DIM + k;
            union { float f[8]; float4 v[2]; } ld;
            ld.v[0] = *(const float4*)(su);
            ld.v[1] = *(const float4*)(su + 4);
            if (n >= 64) {
                #pragma unroll
                for (int j = 0; j < 8; ++j)
                    ld.f[j] *= (float)(k + j + 1) * (1.0f / (float)DIM);
            }
            union { ushort h[8]; uint4 q; } pk;
            #pragma unroll
            for (int j = 0; j < 8; ++j) pk.h[j] = f2h(ld.f[j]);
            *(uint4*)(&Uhl[n * 128 + ((g ^ (n & 7)) * 8)]) = pk.q;
        }
        __syncthreads();

        const int ar = mt * 16 + i16;
        #pragma unroll
        for (int ki = 0; ki < 4; ++ki) {
            const int ga = ki * 4 + quad;
            const v8h a = *(const v8h*)(&Ahl[ar * 128 + ((ga ^ (ar & 7)) * 8)]);
            #pragma unroll
            for (int nt = 0; nt < 4; ++nt) {
                const int n = nh * 64 + nt * 16 + i16;
                const v8h bb = *(const v8h*)(&Uhl[n * 128 + ((ga ^ (n & 7)) * 8)]);
                acc[nt] = __builtin_amdgcn_mfma_f32_16x16x32_f16(a, bb, acc[nt], 0, 0, 0);
            }
        }
    }

    const int vb = row0 + mt * 16 + quad * 4;
    #pragma unroll
    for (int nt = 0; nt < 4; ++nt) {
        const int col = nh * 64 + nt * 16 + i16;
        #pragma unroll
        for (int r = 0; r < 4; ++r)
            Z[(size_t)(vb + r) * 128 + col] = acc[nt][r];
    }
}

// ---------------------------------------------------------------------------
// score[b,s] = sum_w (aw*zu - bw*zd) + TZ[s][b]; softmax over s -> p[b][s].
// grid: BS x 256 (4 waves, 2 sentences per wave-iter).
__global__ __launch_bounds__(256) void k_score(const int*   __restrict__ ctx,
                                               const float* __restrict__ Z,
                                               float*       __restrict__ p) {
    const int b    = blockIdx.x;
    const int tid  = threadIdx.x;
    const int wave = tid >> 6;
    const int lane = tid & 63;
    const int w    = lane & 31;
    const int half = lane >> 5;
    __shared__ float ss[64];

    const float aw = 1.0f - (float)(w + 1) * (1.0f / 32.0f);
    const float bw = 1.0f - (float)(w + 1) * (1.0f / 16.0f);

    #pragma unroll
    for (int i = 0; i < 7; ++i) {
        const int s = i * 8 + wave * 2 + half;
        float val = 0.f;
        if (s < STORY) {
            const int idx = ctx[b * (STORY * SENT) + s * SENT + w];
            if (idx != 0) {
                const float zu = Z[(size_t)idx * 128 + b];
                const float zd = Z[(size_t)idx * 128 + 64 + b];
                val = aw * zu - bw * zd;
            }
        }
        val += __shfl_down(val, 16); val += __shfl_down(val, 8);
        val += __shfl_down(val, 4);  val += __shfl_down(val, 2);
        val += __shfl_down(val, 1);
        if (w == 0 && s < STORY)
            ss[s] = val + Z[(size_t)(VOCAB + s) * 128 + b];   // + T_A[s].u_b
    }
    __syncthreads();

    if (tid < 64) {
        const float v = (tid < STORY) ? ss[tid] : -1e30f;
        float mx = v;
        for (int off = 32; off; off >>= 1) mx = fmaxf(mx, __shfl_down(mx, off));
        mx = __shfl(mx, 0);
        const float e = (tid < STORY) ? __expf(v - mx) : 0.f;
        float sm = e;
        for (int off = 32; off; off >>= 1) sm += __shfl_down(sm, off);
        sm = __shfl(sm, 0);
        p[b * 64 + tid] = e / sm;   // tid >= STORY stores 0
    }
}

// ---------------------------------------------------------------------------
// u[b] += sum_{s,w} p[b,s] * A_{h+1}[ctx[b,s,w]]  (atomicAdd into u).
// grid: BS*4 blocks (b, quarter of words) x 512 (8 waves x 50 words each).
// Each wave reads FULL 2KB rows coalesced (32 B/lane).
__global__ __launch_bounds__(512) void k_cupd(const int*   __restrict__ ctx,
                                              const float* __restrict__ p,
                                              const float* __restrict__ An,
                                              float*       __restrict__ u) {
    const int b    = blockIdx.x >> 2;
    const int q    = blockIdx.x & 3;
    const int tid  = threadIdx.x;
    const int wave = tid >> 6;
    const int lane = tid & 63;
    const int d0   = lane * 8;
    __shared__ float ps[64];
    __shared__ float red[8][DIM];    // 16 KB

    if (tid < 64) ps[tid] = p[b * 64 + tid];
    __syncthreads();

    const int* cb = ctx + b * (STORY * SENT);
    float acc[8];
    #pragma unroll
    for (int j = 0; j < 8; ++j) acc[j] = 0.f;

    const int base = q * 400 + wave * 50;
    #pragma unroll 5
    for (int i = 0; i < 50; ++i) {
        const int t = base + i;
        const int idx = cb[t];
        const float pw = (idx != 0) ? ps[t >> 5] : 0.f;
        const float* row = An + (size_t)idx * DIM + d0;
        const float4 r0 = *(const float4*)(row);
        const float4 r1 = *(const float4*)(row + 4);
        acc[0] = fmaf(pw, r0.x, acc[0]); acc[1] = fmaf(pw, r0.y, acc[1]);
        acc[2] = fmaf(pw, r0.z, acc[2]); acc[3] = fmaf(pw, r0.w, acc[3]);
        acc[4] = fmaf(pw, r1.x, acc[4]); acc[5] = fmaf(pw, r1.y, acc[5]);
        acc[6] = fmaf(pw, r1.z, acc[6]); acc[7] = fmaf(pw, r1.w, acc[7]);
    }
    #pragma unroll
    for (int j = 0; j < 8; ++j) red[wave][d0 + j] = acc[j];
    __syncthreads();

    float s = 0.f;
    #pragma unroll
    for (int wv = 0; wv < 8; ++wv) s += red[wv][tid];
    atomicAdd(&u[(size_t)b * DIM + tid], s);
}

// ---------------------------------------------------------------------------
// logits[b,v] = u_b . A3[v] in exact f32 (VALU). LDS-transposed tiles.
// grid: 500 x 256. Row v=0 forced to 0 (ref zeroes padding row).
#define DCH 64
__global__ __launch_bounds__(256) void k_logits(const float* __restrict__ A3,
                                                const float* __restrict__ u,
                                                float*       __restrict__ out) {
    __shared__ float AT[DCH][64];
    __shared__ float UT[DCH][64];
    const int tid = threadIdx.x;
    const int v0  = blockIdx.x * 64;
    const int vq  = (tid & 15) * 4;     // v offset in tile
    const int bq  = (tid >> 4) * 4;     // b offset
    const int lr  = tid & 63;           // staging row
    const int dg  = tid >> 6;           // staging d-group (0..3)

    float4 acc[4];                      // acc[j] = out[bq+j][v0+vq .. +3]
    #pragma unroll
    for (int j = 0; j < 4; ++j) acc[j] = make_float4(0.f, 0.f, 0.f, 0.f);

    for (int ko = 0; ko < 8; ++ko) {
        __syncthreads();
        #pragma unroll
        for (int k4 = 0; k4 < 4; ++k4) {
            const int dd = dg * 16 + k4 * 4;
            const float4 a = *(const float4*)(A3 + (size_t)(v0 + lr) * DIM + ko * DCH + dd);
            AT[dd + 0][lr] = a.x; AT[dd + 1][lr] = a.y;
            AT[dd + 2][lr] = a.z; AT[dd + 3][lr] = a.w;
            const float4 b = *(const float4*)(u + (size_t)lr * DIM + ko * DCH + dd);
            UT[dd + 0][lr] = b.x; UT[dd + 1][lr] = b.y;
            UT[dd + 2][lr] = b.z; UT[dd + 3][lr] = b.w;
        }
        __syncthreads();
        #pragma unroll 4
        for (int dd = 0; dd < DCH; ++dd) {
            const float4 a4 = *(const float4*)(&AT[dd][vq]);
            const float4 u4 = *(const float4*)(&UT[dd][bq]);
            acc[0].x = fmaf(a4.x, u4.x, acc[0].x); acc[0].y = fmaf(a4.y, u4.x, acc[0].y);
            acc[0].z = fmaf(a4.z, u4.x, acc[0].z); acc[0].w = fmaf(a4.w, u4.x, acc[0].w);
            acc[1].x = fmaf(a4.x, u4.y, acc[1].x); acc[1].y = fmaf(a4.y, u4.y, acc[1].y);
            acc[1].z = fmaf(a4.z, u4.y, acc[1].z); acc[1].w = fmaf(a4.w, u4.y, acc[1].w);
            acc[2].x = fmaf(a4.x, u4.z, acc[2].x); acc[2].y = fmaf(a4.y, u4.z, acc[2].y);
            acc[2].z = fmaf(a4.z, u4.z, acc[2].z); acc[2].w = fmaf(a4.w, u4.z, acc[2].w);
            acc[3].x = fmaf(a4.x, u4.w, acc[3].x); acc[3].y = fmaf(a4.y, u4.w, acc[3].y);
            acc[3].z = fmaf(a4.z, u4.w, acc[3].z); acc[3].w = fmaf(a4.w, u4.w, acc[3].w);
        }
    }

    if (v0 + vq == 0) {   // padding row: logits[:,0] = 0
        acc[0].x = 0.f; acc[1].x = 0.f; acc[2].x = 0.f; acc[3].x = 0.f;
    }
    #pragma unroll
    for (int j = 0; j < 4; ++j)
        *(float4*)(out + (size_t)(bq + j) * VOCAB + v0 + vq) = acc[j];
}

// ---------------------------------------------------------------------------
// in-place row softmax over VOCAB; row cached in registers, exp computed once.
__global__ __launch_bounds__(1024) void k_vsm(float* __restrict__ out) {
    const int b   = blockIdx.x;
    const int tid = threadIdx.x;
    float* row = out + (size_t)b * VOCAB;
    __shared__ float red[16];
    __shared__ float bc;

    float x[32];
    #pragma unroll
    for (int k = 0; k < 31; ++k) x[k] = row[tid + k * 1024];
    const bool extra = (tid < VOCAB - 31 * 1024);
    x[31] = extra ? row[tid + 31 * 1024] : -1e30f;

    float mx = -1e30f;
    #pragma unroll
    for (int k = 0; k < 32; ++k) mx = fmaxf(mx, x[k]);
    for (int off = 32; off; off >>= 1) mx = fmaxf(mx, __shfl_down(mx, off));
    if ((tid & 63) == 0) red[tid >> 6] = mx;
    __syncthreads();
    if (tid < 64) {
        float v = (tid < 16) ? red[tid] : -1e30f;
        for (int off = 8; off; off >>= 1) v = fmaxf(v, __shfl_down(v, off));
        if (tid == 0) bc = v;
    }
    __syncthreads();
    mx = bc;
    __syncthreads();

    float sum = 0.f;
    #pragma unroll
    for (int k = 0; k < 32; ++k) { x[k] = __expf(x[k] - mx); sum += x[k]; }
    if (!extra) sum -= x[31];
    for (int off = 32; off; off >>= 1) sum += __shfl_down(sum, off);
    if ((tid & 63) == 0) red[tid >> 6] = sum;
    __syncthreads();
    if (tid < 64) {
        float v = (tid < 16) ? red[tid] : 0.f;
        for (int off = 8; off; off >>= 1) v += __shfl_down(v, off);
        if (tid == 0) bc = v;
    }
    __syncthreads();
    const float inv = 1.0f / bc;

    #pragma unroll
    for (int k = 0; k < 31; ++k) row[tid + k * 1024] = x[k] * inv;
    if (extra) row[tid + 31 * 1024] = x[31] * inv;
}

// ---------------------------------------------------------------------------
extern "C" void kernel_launch(void* const* d_in, const int* in_sizes, int n_in,
                              void* d_out, int out_size, void* d_ws, size_t ws_size,
                              hipStream_t stream) {
    const int*   ctx   = (const int*)d_in[0];    // (BS, STORY, SENT)
    const int*   query = (const int*)d_in[1];    // (BS, QLEN)
    const float* A     = (const float*)d_in[2];  // (4, VOCAB, DIM)
    const float* T_A   = (const float*)d_in[3];  // (1, MEM, DIM)
    float* out = (float*)d_out;                  // (BS, VOCAB)

    float* u = (float*)d_ws;                     // 64*512 f32
    float* p = u + BS * DIM;                     // 64*64 f32
    float* Z = p + BS * 64;                      // 32064*128 f32 (~16.4 MB)

    k_prep<<<BS, DIM, 0, stream>>>(A, query, u);
    for (int h = 0; h < NUM_HOP; ++h) {
        k_z    <<<1002, 256, 0, stream>>>(A + (size_t)h * TBL, T_A, u, Z);
        k_score<<<BS, 256, 0, stream>>>(ctx, Z, p);
        k_cupd <<<BS * 4, 512, 0, stream>>>(ctx, p, A + (size_t)(h + 1) * TBL, u);
    }
    k_logits<<<500, 256, 0, stream>>>(A + 3 * TBL, u, out);
    k_vsm  <<<BS, 1024, 0, stream>>>(out);
}